// Round 15
// baseline (70.246 us; speedup 1.0000x reference)
//
#include <hip/hip_runtime.h>
#include <math.h>

#define HB 256   // hidden
#define UB 128   // attention units
#define BB 16    // batch
#define TD 128   // decoder steps
#define TE 1024  // encoder steps

#define CLAMP_W 7.0f
#define L2E2 2.8853900817779268f        // 2*log2(e)
#define ALPHA 1.52587890625e-05f        // 2^-16 (folded into Ea)
#define NEG2ALPHA (-3.0517578125e-05f)  // -2*ALPHA

// zero-instruction scheduling pins (v8-proven)
#define PINV(x) asm volatile("" : "+v"(x))
#define PINS(x) asm volatile("" : "+s"(x))
#define PINV4(q) do { PINV((q).x); PINV((q).y); PINV((q).z); PINV((q).w); } while (0)
#define PINS4(q) do { PINS((q).x); PINS((q).y); PINS((q).z); PINS((q).w); } while (0)

typedef __attribute__((ext_vector_type(8))) short bf16x8;
typedef __attribute__((ext_vector_type(4))) float f32x4;

__device__ __forceinline__ unsigned short f2bf(float x) {   // RNE f32->bf16
    union { float f; unsigned u; } v; v.f = x;
    unsigned r = v.u + 0x7FFFu + ((v.u >> 16) & 1u);
    return (unsigned short)(r >> 16);
}
__device__ __forceinline__ float bf2f(unsigned short h) {
    union { float f; unsigned u; } v; v.u = ((unsigned)h) << 16;
    return v.f;
}

// staged operand: exp2(2*log2e*clamp(w,+-7) + shift); tanh(a+e)=1-2/(EaEb+1).
__device__ __forceinline__ float stage_exp(float w, float shift) {
    float t = fminf(fmaxf(w, -CLAMP_W), CLAMP_W);
    return exp2f(fmaf(t, L2E2, shift));
}

// ---------------- projections via MFMA (bf16 hi/lo x3 split) ----------------
// Block 256 thr = 4 waves; block = 64-row slab x 16-u tile. X staged in LDS as
// bf16 hi/lo ([64][264] pad: A-frag b128 reads bank-balanced); W fragments
// (16u x 256k, hi/lo) gathered once into 64 VGPR. Per wave: 16 rows x 16 u,
// 8 K-steps x 3 MFMAs (XhWh + XhWl + XlWh; dropped XlWl ~2^-18 rel).
// 3 independent acc chains. Epilogue: bias + clamp + exp2, write [b][u4][pos][4]
// via verified C/D map (col=lane&15, row=(lane>>4)*4+reg).
#define SLABS 288                     // 32 dec + 256 enc 64-row slabs
#define PROJ_BLOCKS (SLABS * 8)       // x8 u-tiles = 2304

__global__ __launch_bounds__(256) void proj_mfma(
    const float* __restrict__ dec, const float* __restrict__ enc,
    const float* __restrict__ W1, const float* __restrict__ b1,
    const float* __restrict__ W2, const float* __restrict__ b2,
    float* __restrict__ Ea, float* __restrict__ Eb) {
    const int bid  = blockIdx.x;
    const int slab = bid >> 3;           // slab-major: 8 u-tiles share X slab
    const int ut   = bid & 7;
    const bool is_dec = slab < 32;
    const int rel = is_dec ? slab : slab - 32;
    const float* __restrict__ X    = is_dec ? dec : enc;
    const float* __restrict__ W    = is_dec ? W1 : W2;
    const float* __restrict__ bias = is_dec ? b1 : b2;

    __shared__ unsigned short xh[64][264];   // 33.8 KB each (pad 264)
    __shared__ unsigned short xl[64][264];

    const int tid = threadIdx.x;
    const long row0 = (long)rel * 64;

    // stage + split X: 64 rows x 256 k, coalesced float4 reads
    #pragma unroll
    for (int it = 0; it < 16; ++it) {
        int idx = it * 256 + tid;            // float4 index over [64][64]
        int r = idx >> 6, c4 = idx & 63;
        float4 f = *reinterpret_cast<const float4*>(X + (row0 + r) * HB + c4 * 4);
        unsigned short h0 = f2bf(f.x), h1 = f2bf(f.y), h2 = f2bf(f.z), h3 = f2bf(f.w);
        *reinterpret_cast<ushort4*>(&xh[r][c4 * 4]) = make_ushort4(h0, h1, h2, h3);
        unsigned short l0 = f2bf(f.x - bf2f(h0)), l1 = f2bf(f.y - bf2f(h1));
        unsigned short l2 = f2bf(f.z - bf2f(h2)), l3 = f2bf(f.w - bf2f(h3));
        *reinterpret_cast<ushort4*>(&xl[r][c4 * 4]) = make_ushort4(l0, l1, l2, l3);
    }

    // gather W fragments into VGPRs (once per block; L1/L2-shared across waves)
    const int l  = tid & 63;
    const int wv = tid >> 6;                 // wave -> rows wv*16..+15
    const int ucol = ut * 16 + (l & 15);     // B free dim on lane%16
    const int kg = (l >> 4) * 8;             // k-group on lane/16

    bf16x8 bh[8], bl[8];
    #pragma unroll
    for (int s = 0; s < 8; ++s) {
        const float* wp = W + (32 * s + kg) * UB + ucol;
        short hb[8], lb[8];
        #pragma unroll
        for (int j = 0; j < 8; ++j) {
            float w = wp[j * UB];
            unsigned short h = f2bf(w);
            hb[j] = (short)h;
            lb[j] = (short)f2bf(w - bf2f(h));
        }
        bh[s] = (bf16x8){hb[0], hb[1], hb[2], hb[3], hb[4], hb[5], hb[6], hb[7]};
        bl[s] = (bf16x8){lb[0], lb[1], lb[2], lb[3], lb[4], lb[5], lb[6], lb[7]};
    }
    __syncthreads();

    f32x4 acc0 = {0.f, 0.f, 0.f, 0.f};
    f32x4 acc1 = {0.f, 0.f, 0.f, 0.f};
    f32x4 acc2 = {0.f, 0.f, 0.f, 0.f};
    const int arow = wv * 16 + (l & 15);     // A free dim on lane%16

    #pragma unroll
    for (int s = 0; s < 8; ++s) {
        bf16x8 ah = *reinterpret_cast<const bf16x8*>(&xh[arow][32 * s + kg]);
        bf16x8 al = *reinterpret_cast<const bf16x8*>(&xl[arow][32 * s + kg]);
        acc0 = __builtin_amdgcn_mfma_f32_16x16x32_bf16(ah, bh[s], acc0, 0, 0, 0);
        acc1 = __builtin_amdgcn_mfma_f32_16x16x32_bf16(ah, bl[s], acc1, 0, 0, 0);
        acc2 = __builtin_amdgcn_mfma_f32_16x16x32_bf16(al, bh[s], acc2, 0, 0, 0);
    }

    const float bv = bias[ucol];
    const float sh = is_dec ? -16.f : 0.f;
    const int POS  = is_dec ? TD : TE;
    const long bq  = row0 / POS;
    const int posb = (int)(row0 % POS) + wv * 16 + (l >> 4) * 4;  // C row
    float* __restrict__ dst = is_dec ? Ea : Eb;
    const long ubase = (bq * 32 + (ucol >> 2)) * (long)POS;
    #pragma unroll
    for (int q = 0; q < 4; ++q) {
        float v = acc0[q] + acc1[q] + acc2[q] + bv;
        dst[(ubase + posb + q) * 4 + (ucol & 3)] = stage_exp(v, sh);
    }
}

// ---------------- scores + fused softmax (R13/R14, best-measured) ----------
__global__ __launch_bounds__(1024) void score_v13(
    const float* __restrict__ Ea4,   // [B][32][TD][4], 2^-16-scaled
    const float4* __restrict__ Eb4,  // [B][32][TE]
    const float* __restrict__ V,     // [UB]
    float* __restrict__ out) {       // [B, TD, TE]
    const int tid = threadIdx.x;
    const int wv = tid >> 6, l = tid & 63;
    const int i = blockIdx.x;
    const int b  = 2 * (i & 7) + ((i >> 3) >> 4);
    const int t0 = ((i >> 3) & 15) * 8;

    const float*  ab = Ea4 + ((long)b * 32 * TD) * 4;
    const float4* ep = Eb4 + (long)b * 32 * TE + tid;
    const float alphav = ALPHA;

    float acc[8];
    #pragma unroll
    for (int t = 0; t < 8; ++t) acc[t] = 0.f;

    float4 aC[8], aN[8], vC, vN, e0, e1, e2;
#define ALOAD(AB, VB, U4) do {                                            \
        const float* _a = ab + ((long)(U4) * TD + t0) * 4;                \
        _Pragma("unroll")                                                 \
        for (int t = 0; t < 8; ++t)                                       \
            AB[t] = *reinterpret_cast<const float4*>(_a + t * 4);         \
        VB = *reinterpret_cast<const float4*>(V + (U4) * 4);              \
    } while (0)

#define SCOMP(AB, VB, EB) do {                                            \
        _Pragma("unroll")                                                 \
        for (int t = 0; t < 8; ++t) {                                     \
            float4 A = AB[t];                                             \
            float X0 = fmaf(A.x, (EB).x, alphav);                         \
            float X1 = fmaf(A.y, (EB).y, alphav);                         \
            float X2 = fmaf(A.z, (EB).z, alphav);                         \
            float X3 = fmaf(A.w, (EB).w, alphav);                         \
            float P01 = X0 * X1, P23 = X2 * X3;                           \
            float N01 = fmaf((VB).x, X1, (VB).y * X0);                    \
            float N23 = fmaf((VB).z, X3, (VB).w * X2);                    \
            float N   = fmaf(N01, P23, N23 * P01);                        \
            acc[t] = fmaf(N, __builtin_amdgcn_rcpf(P01 * P23), acc[t]);   \
        }                                                                 \
    } while (0)

    ALOAD(aC, vC, 0);
    e0 = ep[0];
    e1 = ep[TE];
    #pragma unroll 2
    for (int u4 = 0; u4 < 32; ++u4) {
        const int p1 = (u4 + 1 < 32) ? u4 + 1 : 0;
        const int p2 = (u4 + 2 < 32) ? u4 + 2 : 0;
        e2 = ep[(long)p2 * TE];
        ALOAD(aN, vN, p1);
        SCOMP(aC, vC, e0);
        #pragma unroll
        for (int t = 0; t < 8; ++t) PINS4(aN[t]);
        PINS4(vN);
        PINV4(e2);
        #pragma unroll
        for (int t = 0; t < 8; ++t) aC[t] = aN[t];
        vC = vN;
        e0 = e1; e1 = e2;
    }
#undef ALOAD
#undef SCOMP

    float sc[8];
    #pragma unroll
    for (int t = 0; t < 8; ++t) sc[t] = NEG2ALPHA * acc[t];

    __shared__ float red[8][16];
    #pragma unroll
    for (int t = 0; t < 8; ++t) {
        float x = sc[t];
        #pragma unroll
        for (int off = 32; off > 0; off >>= 1) x = fmaxf(x, __shfl_xor(x, off, 64));
        if (l == 0) red[t][wv] = x;
    }
    __syncthreads();
    float m[8];
    #pragma unroll
    for (int t = 0; t < 8; ++t) {
        float x = red[t][0];
        #pragma unroll
        for (int k = 1; k < 16; ++k) x = fmaxf(x, red[t][k]);
        m[t] = x;
    }
    __syncthreads();
    #pragma unroll
    for (int t = 0; t < 8; ++t) {
        sc[t] = __expf(sc[t] - m[t]);
        float x = sc[t];
        #pragma unroll
        for (int off = 32; off > 0; off >>= 1) x += __shfl_xor(x, off, 64);
        if (l == 0) red[t][wv] = x;
    }
    __syncthreads();
    #pragma unroll
    for (int t = 0; t < 8; ++t) {
        float x = red[t][0];
        #pragma unroll
        for (int k = 1; k < 16; ++k) x += red[t][k];
        out[((long)b * TD + t0 + t) * TE + tid] = sc[t] * (1.f / x);
    }
}

extern "C" void kernel_launch(void* const* d_in, const int* in_sizes, int n_in,
                              void* d_out, int out_size, void* d_ws, size_t ws_size,
                              hipStream_t stream) {
    const float* dec = (const float*)d_in[0];
    const float* enc = (const float*)d_in[1];
    const float* W1  = (const float*)d_in[2];
    const float* b1  = (const float*)d_in[3];
    const float* W2  = (const float*)d_in[4];
    const float* b2  = (const float*)d_in[5];
    const float* V   = (const float*)d_in[6];
    // d_in[7] = bv : softmax-invariant, unused
    float* out = (float*)d_out;

    float* Ea = (float*)d_ws;                  // [B][32][TD][4]  1 MB (2^-16-scaled)
    float* Eb = Ea + (long)BB * 32 * TD * 4;   // [B][32][TE][4]  8 MB

    proj_mfma<<<PROJ_BLOCKS, 256, 0, stream>>>(dec, enc, W1, b1, W2, b2, Ea, Eb);
    score_v13<<<256, 1024, 0, stream>>>(Ea, (const float4*)Eb, V, out);
}

// Round 16
// 67.860 us; speedup vs baseline: 1.0352x; 1.0352x over previous
//
#include <hip/hip_runtime.h>
#include <math.h>

#define HB 256   // hidden
#define UB 128   // attention units
#define BB 16    // batch
#define TD 128   // decoder steps
#define TE 1024  // encoder steps

#define CLAMP_W 7.0f
#define L2E2 2.8853900817779268f        // 2*log2(e)
#define ALPHA 1.52587890625e-05f        // 2^-16 (folded into Ea)
#define NEG2ALPHA (-3.0517578125e-05f)  // -2*ALPHA

// zero-instruction scheduling pins (v8-proven): force load completed here.
#define PINV(x) asm volatile("" : "+v"(x))
#define PINS(x) asm volatile("" : "+s"(x))
#define PINV4(q) do { PINV((q).x); PINV((q).y); PINV((q).z); PINV((q).w); } while (0)
#define PINS4(q) do { PINS((q).x); PINS((q).y); PINS((q).z); PINS((q).w); } while (0)

// staged operand: exp2(2*log2e*clamp(w,+-7) + shift); tanh(a+e)=1-2/(EaEb+1).
// clamp +-7 never triggers on this data; shift=-16 scales Ea so the 4-way
// merged denominator stays bounded. Numerics identical to R4..R15 (passed).
__device__ __forceinline__ float stage_exp(float w, float shift) {
    float t = fminf(fmaxf(w, -CLAMP_W), CLAMP_W);
    return exp2f(fmaf(t, L2E2, shift));
}

// ---------------- projections (dec + enc, one grid; R12-measured best) -----
// Wave = u16-block (W wave-uniform -> scalar pipe, zero LDS/VMEM in hot loop)
// x lanes = 64 rows (X from transposed LDS tile xt[h][row]: 4 conflict-free
// ds_read_b32 per 4-h step). Waves split h in halves (LDS partial reduce);
// blocks split u in halves.
#define DEC_SLABS 32                 // 2048 rows / 64
#define NSLABS 288                   // + 16384/64 enc slabs
#define PROJ_BLOCKS (NSLABS * 2)     // x2 u-halves = 576

__global__ __launch_bounds__(512) void proj_v12(
    const float* __restrict__ dec, const float* __restrict__ enc,
    const float* __restrict__ W1, const float* __restrict__ b1,
    const float* __restrict__ W2, const float* __restrict__ b2,
    float* __restrict__ Ea, float* __restrict__ Eb) {
    const int blk = blockIdx.x;
    const int slab = blk >> 1, uhalf = blk & 1;
    const bool is_dec = slab < DEC_SLABS;
    const int rel = is_dec ? slab : slab - DEC_SLABS;
    const float* __restrict__ X    = is_dec ? dec : enc;
    const float* __restrict__ W    = is_dec ? W1 : W2;
    const float* __restrict__ bias = is_dec ? b1 : b2;

    __shared__ float xt[HB][66];     // transposed X tile [h][row]
    const int tid = threadIdx.x;
    const long row0 = (long)rel * 64;

    #pragma unroll
    for (int it = 0; it < 8; ++it) {  // stage+transpose 64 rows x 256 h
        int idx = it * 512 + tid;
        int row = idx >> 6, hf4 = idx & 63;
        float4 f = *reinterpret_cast<const float4*>(X + (row0 + row) * HB + hf4 * 4);
        xt[hf4 * 4 + 0][row] = f.x;
        xt[hf4 * 4 + 1][row] = f.y;
        xt[hf4 * 4 + 2][row] = f.z;
        xt[hf4 * 4 + 3][row] = f.w;
    }
    __syncthreads();

    const int l = tid & 63;                                     // row in slab
    const int w = __builtin_amdgcn_readfirstlane(tid >> 6);     // wave 0..7
    const int ub3 = w & 3;                                      // u16 within half
    const int ub  = ub3 + uhalf * 4;                            // 0..7
    const int hh  = w >> 2;                                     // h-half 0/1
    const int u0  = ub * 16;
    const int h0  = hh * 128;

    float acc[16];
    #pragma unroll
    for (int j = 0; j < 16; ++j) acc[j] = 0.f;

    for (int h = 0; h < 128; h += 4) {
        const int hg = h0 + h;
        float4 wf[4][4];                 // wave-uniform -> scalar loads
        #pragma unroll
        for (int k = 0; k < 4; ++k)
            #pragma unroll
            for (int q = 0; q < 4; ++q)
                wf[k][q] = *reinterpret_cast<const float4*>(
                    W + (hg + k) * UB + u0 + q * 4);
        float xk[4];
        #pragma unroll
        for (int k = 0; k < 4; ++k) xk[k] = xt[hg + k][l];   // b32, conflict-free
        #pragma unroll
        for (int k = 0; k < 4; ++k)
            #pragma unroll
            for (int q = 0; q < 4; ++q) {
                acc[q * 4 + 0] = fmaf(xk[k], wf[k][q].x, acc[q * 4 + 0]);
                acc[q * 4 + 1] = fmaf(xk[k], wf[k][q].y, acc[q * 4 + 1]);
                acc[q * 4 + 2] = fmaf(xk[k], wf[k][q].z, acc[q * 4 + 2]);
                acc[q * 4 + 3] = fmaf(xk[k], wf[k][q].w, acc[q * 4 + 3]);
            }
    }

    __syncthreads();                     // xt reads done; reuse as reduce buf
    float4* red = reinterpret_cast<float4*>(&xt[0][0]);   // 4ub x 64row x 4 f4
    if (hh == 1) {
        #pragma unroll
        for (int q = 0; q < 4; ++q)
            red[((ub3 * 64 + l) << 2) + q] =
                make_float4(acc[q * 4], acc[q * 4 + 1], acc[q * 4 + 2], acc[q * 4 + 3]);
    }
    __syncthreads();
    if (hh == 0) {
        #pragma unroll
        for (int q = 0; q < 4; ++q) {
            float4 r = red[((ub3 * 64 + l) << 2) + q];
            acc[q * 4 + 0] += r.x; acc[q * 4 + 1] += r.y;
            acc[q * 4 + 2] += r.z; acc[q * 4 + 3] += r.w;
        }
        const float sh = is_dec ? -16.f : 0.f;
        const int POS  = is_dec ? TD : TE;
        const long bq  = row0 / POS;
        const int pos  = (int)(row0 % POS) + l;
        float4* dst4 = reinterpret_cast<float4*>(is_dec ? Ea : Eb);
        #pragma unroll
        for (int q = 0; q < 4; ++q) {    // u4 = ub*4+q, layout [b][u4][pos][4]
            float4 o = make_float4(
                stage_exp(acc[q * 4 + 0] + bias[u0 + q * 4 + 0], sh),
                stage_exp(acc[q * 4 + 1] + bias[u0 + q * 4 + 1], sh),
                stage_exp(acc[q * 4 + 2] + bias[u0 + q * 4 + 2], sh),
                stage_exp(acc[q * 4 + 3] + bias[u0 + q * 4 + 3], sh));
            dst4[(bq * 32 + ub * 4 + q) * (long)POS + pos] = o;   // coalesced
        }
    }
}

// ---------------- raw scores (TT=16; R9-measured best ~21us) ----------------
// Grid 256 = [b16][tgrp8][shalf2]; block 512 thr; s = shalf*512 + tid;
// thread owns 16 t-rows. Per u4-iter: a-tile (block-uniform -> scalar loads)
// single-buffered with pin-drain; e (per-lane coalesced dwordx4) + V depth-1.
__global__ __launch_bounds__(512) void score_v9(
    const float* __restrict__ Ea4,   // [B][32][TD][4], 2^-16-scaled
    const float4* __restrict__ Eb4,  // [B][32][TE]
    const float* __restrict__ V,     // [UB]
    float* __restrict__ outraw) {    // [B, TD, TE] raw scores
    const int tid = threadIdx.x;
    const int i = blockIdx.x;
    const int xcd = i & 7, j = i >> 3;          // XCD-pinned: 2 b per XCD
    const int b     = 2 * xcd + (j >> 4);
    const int tgrp  = (j >> 1) & 7;
    const int shalf = j & 1;
    const int t0 = tgrp * 16;
    const int s  = shalf * 512 + tid;

    const float*  ab = Ea4 + ((long)b * 32 * TD + t0) * 4;   // + u4*TD*4
    const float4* ep = Eb4 + (long)b * 32 * TE + s;          // + u4*TE
    const float alphav = ALPHA;

    float acc[16];
    #pragma unroll
    for (int t = 0; t < 16; ++t) acc[t] = 0.f;

    float4 a[16], vC, vN, eC, eN;
    vC = *reinterpret_cast<const float4*>(V);
    eC = ep[0];

    for (int u4 = 0; u4 < 32; ++u4) {
        const int p = (u4 + 1 < 32) ? u4 + 1 : 0;   // wrap: harmless reload
        eN = ep[(long)p * TE];
        vN = *reinterpret_cast<const float4*>(V + p * 4);
        const float* _a = ab + (long)u4 * (TD * 4);
        #pragma unroll
        for (int t = 0; t < 16; ++t)
            a[t] = *reinterpret_cast<const float4*>(_a + t * 4);  // uniform
        PINS4(a[15]);   // last-issued: waiting on it drains all a-loads
        #pragma unroll
        for (int t = 0; t < 16; ++t) {
            float4 A = a[t];
            float X0 = fmaf(A.x, eC.x, alphav);
            float X1 = fmaf(A.y, eC.y, alphav);
            float X2 = fmaf(A.z, eC.z, alphav);
            float X3 = fmaf(A.w, eC.w, alphav);
            float P01 = X0 * X1, P23 = X2 * X3;
            float N01 = fmaf(vC.x, X1, vC.y * X0);
            float N23 = fmaf(vC.z, X3, vC.w * X2);
            float N   = fmaf(N01, P23, N23 * P01);
            acc[t] = fmaf(N, __builtin_amdgcn_rcpf(P01 * P23), acc[t]);
        }
        PINV4(eN);
        PINS4(vN);
        eC = eN; vC = vN;
    }

    float* orow = outraw + ((long)b * TD + t0) * TE + s;
    #pragma unroll
    for (int t = 0; t < 16; ++t)
        orow[(long)t * TE] = NEG2ALPHA * acc[t];    // coalesced per row
}

// ---------------- in-place row softmax on d_out (R9-measured) ----------------
__global__ __launch_bounds__(1024) void softmax_v9(float* __restrict__ out) {
    const long row = blockIdx.x;             // b*TD + t
    float* p = out + row * TE;
    const int tid = threadIdx.x;
    const int wv = tid >> 6, l = tid & 63;

    float x = p[tid];
    __shared__ float red[16];
    float m = x;
    #pragma unroll
    for (int off = 32; off > 0; off >>= 1) m = fmaxf(m, __shfl_xor(m, off, 64));
    if (l == 0) red[wv] = m;
    __syncthreads();
    #pragma unroll
    for (int k = 0; k < 16; ++k) m = fmaxf(m, red[k]);
    __syncthreads();
    float e = __expf(x - m);
    float si = e;
    #pragma unroll
    for (int off = 32; off > 0; off >>= 1) si += __shfl_xor(si, off, 64);
    if (l == 0) red[wv] = si;
    __syncthreads();
    si = 0.f;
    #pragma unroll
    for (int k = 0; k < 16; ++k) si += red[k];
    p[tid] = e * (1.f / si);
}

extern "C" void kernel_launch(void* const* d_in, const int* in_sizes, int n_in,
                              void* d_out, int out_size, void* d_ws, size_t ws_size,
                              hipStream_t stream) {
    const float* dec = (const float*)d_in[0];
    const float* enc = (const float*)d_in[1];
    const float* W1  = (const float*)d_in[2];
    const float* b1  = (const float*)d_in[3];
    const float* W2  = (const float*)d_in[4];
    const float* b2  = (const float*)d_in[5];
    const float* V   = (const float*)d_in[6];
    // d_in[7] = bv : softmax-invariant, unused
    float* out = (float*)d_out;

    float* Ea = (float*)d_ws;                  // [B][32][TD][4]  1 MB (2^-16-scaled)
    float* Eb = Ea + (long)BB * 32 * TD * 4;   // [B][32][TE][4]  8 MB

    proj_v12<<<PROJ_BLOCKS, 512, 0, stream>>>(dec, enc, W1, b1, W2, b2, Ea, Eb);
    score_v9<<<256, 512, 0, stream>>>(Ea, (const float4*)Eb, V, out);
    softmax_v9<<<BB * TD, 1024, 0, stream>>>(out);
}